// Round 8
// baseline (396.743 us; speedup 1.0000x reference)
//
#include <hip/hip_runtime.h>
#include <cmath>

#define NNODES 20000
#define NEDGES 640000
#define DDIM   128
#define TN     16    // nodes per block in qk kernel
#define BE     16    // edges per (single-wave) edge block

typedef __attribute__((ext_vector_type(8))) short bf16x8;
typedef __attribute__((ext_vector_type(4))) float f32x4;
typedef __attribute__((ext_vector_type(4))) unsigned short us4;
typedef __attribute__((ext_vector_type(8))) unsigned short us8;

union U4B { uint4 u; bf16x8 b; };

__device__ __forceinline__ unsigned short f2bf(float x) {
    union { float f; unsigned u; } v; v.f = x;
    unsigned r = v.u + 0x7FFFu + ((v.u >> 16) & 1u);   // RNE
    return (unsigned short)(r >> 16);
}
__device__ __forceinline__ float bf2f(unsigned short h) {
    union { unsigned u; float f; } v; v.u = ((unsigned)h) << 16; return v.f;
}
// packed bf16 pair via HW instruction: D[15:0]=bf16(lo), D[31:16]=bf16(hi)
__device__ __forceinline__ unsigned cvtpk(float lo, float hi) {
    unsigned r;
    asm("v_cvt_pk_bf16_f32 %0, %1, %2" : "=v"(r) : "v"(lo), "v"(hi));
    return r;
}

// ---------------------------------------------------------------------------
// Pack fp32 weight matrix [K x 128] into bf16 MFMA A-fragment layout.
// frame f = kt*8 + nt; elem (lane,i): W[kt*32 + (lane>>4)*8 + i][nt*16 + (lane&15)]
// ---------------------------------------------------------------------------
__global__ void pack_weights(const float* __restrict__ W, unsigned short* __restrict__ dst)
{
    const int f  = blockIdx.x;
    const int kt = f >> 3, nt = f & 7;
    const int t  = threadIdx.x;
#pragma unroll
    for (int ii = 0; ii < 2; ii++) {
        const int idx  = t * 2 + ii;          // 0..511
        const int lane = idx >> 3, i = idx & 7;
        const int k = kt * 32 + (lane >> 4) * 8 + i;
        const int n = nt * 16 + (lane & 15);
        dst[f * 512 + idx] = f2bf(W[k * 128 + n]);
    }
}

// ---------------------------------------------------------------------------
// q = node_feats @ Wq, k = node_feats @ Wk  -> bf16 [N,128] each.
// ---------------------------------------------------------------------------
__global__ __launch_bounds__(256) void qk_proj_kernel(
    const float* __restrict__ nf, const float* __restrict__ Wq,
    const float* __restrict__ Wk, unsigned short* __restrict__ qbuf,
    unsigned short* __restrict__ kbuf)
{
    __shared__ float s_nf[TN * DDIM];
    const int t  = threadIdx.x;
    const int n0 = blockIdx.x * TN;
    {
        const float4* src = (const float4*)(nf + (size_t)n0 * DDIM);
        float4* dst = (float4*)s_nf;
        for (int i = t; i < TN * DDIM / 4; i += 256) dst[i] = src[i];
    }
    __syncthreads();

    const int j = t & 127;
    const float* W = (t < 128) ? Wq : Wk;
    float acc[TN];
#pragma unroll
    for (int n = 0; n < TN; n++) acc[n] = 0.f;

    for (int k = 0; k < DDIM; k += 4) {
        const float w0 = W[(k + 0) * DDIM + j];
        const float w1 = W[(k + 1) * DDIM + j];
        const float w2 = W[(k + 2) * DDIM + j];
        const float w3 = W[(k + 3) * DDIM + j];
#pragma unroll
        for (int n = 0; n < TN; n++) {
            const float4 f = *(const float4*)&s_nf[n * DDIM + k];
            acc[n] = fmaf(f.w, w3, fmaf(f.z, w2, fmaf(f.y, w1, fmaf(f.x, w0, acc[n]))));
        }
    }
    unsigned short* outp = (t < 128) ? qbuf : kbuf;
    for (int n = 0; n < TN; n++) outp[(size_t)(n0 + n) * DDIM + j] = f2bf(acc[n]);
}

// ---------------------------------------------------------------------------
// Single-wave fused edge kernel: 16 edges per 64-thread block, NO barriers.
// Lane l: edge e = l&15, col-group cg = l>>4.
// mfma(W_frag(A), edge_frag(B)) -> C frag: lane = edge (l&15), cols cg*4+reg
// (+16 per col-tile). All LDS use is wave-private (lgkmcnt only).
// ---------------------------------------------------------------------------
__global__ __launch_bounds__(64, 4) void edge_kernel(
    const float* __restrict__ edge_sh, const float* __restrict__ cutoffs,
    const int* __restrict__ senders, const int* __restrict__ receivers,
    const float* __restrict__ edge_feats, const float* __restrict__ chi_scalar,
    const unsigned short* __restrict__ w1r, const unsigned short* __restrict__ w1s,
    const unsigned short* __restrict__ w2r, const unsigned short* __restrict__ w2s,
    const float* __restrict__ b_rad1, const float* __restrict__ b_sph1,
    const float* __restrict__ b_rad2, const float* __restrict__ b_sph2,
    const unsigned short* __restrict__ qbuf, const unsigned short* __restrict__ kbuf,
    float* __restrict__ out)
{
    __shared__ unsigned short s_p[BE * 128];   // 4 KB  [edge][c] = q*k, swizzled
    __shared__ unsigned short s_h[BE * 128];   // 4 KB  [edge][hid],     swizzled
    char* pp = (char*)s_p;
    char* ph = (char*)s_h;

    const int l  = threadIdx.x;
    const int e  = l & 15;
    const int cg = l >> 4;               // 0..3
    const int eb = blockIdx.x * BE;
    const int eg = eb + e;
    const int sw = (e & 7) << 4;         // XOR swizzle within 128B wrap

    const int rn   = receivers[eg];
    const int sn   = senders[eg];
    const float cut = cutoffs[eg];

    // ---- Phase P: gather bf16 q,k rows; p = q*k -> LDS (consumed at the end;
    //      the whole MLP hides this latency) ----
    {
        const unsigned short* qrow = qbuf + (size_t)rn * 128 + cg * 32;
        const unsigned short* krow = kbuf + (size_t)sn * 128 + cg * 32;
#pragma unroll
        for (int j = 0; j < 4; j++) {
            const us8 qv = *(const us8*)(qrow + j * 8);
            const us8 kv = *(const us8*)(krow + j * 8);
            uint4 pv;
            pv.x = cvtpk(bf2f(qv[0]) * bf2f(kv[0]), bf2f(qv[1]) * bf2f(kv[1]));
            pv.y = cvtpk(bf2f(qv[2]) * bf2f(kv[2]), bf2f(qv[3]) * bf2f(kv[3]));
            pv.z = cvtpk(bf2f(qv[4]) * bf2f(kv[4]), bf2f(qv[5]) * bf2f(kv[5]));
            pv.w = cvtpk(bf2f(qv[6]) * bf2f(kv[6]), bf2f(qv[7]) * bf2f(kv[7]));
            *(uint4*)(pp + ((e * 256 + cg * 64 + j * 16) ^ sw)) = pv;
        }
    }

    // ---- MLP: both paths accumulate final w cols into acc2 ----
    f32x4 acc2[8];
#pragma unroll
    for (int i = 0; i < 8; i++) acc2[i] = (f32x4){0.f, 0.f, 0.f, 0.f};

#pragma unroll
    for (int path = 0; path < 2; path++) {
        const unsigned short* W1p = path ? w1s : w1r;
        const unsigned short* W2p = path ? w2s : w2r;
        const float* b1p = path ? b_sph1 : b_rad1;
        const float* inp = path ? chi_scalar : edge_feats;

        // L1 B-frags straight from global fp32 (no LDS staging):
        // lane l holds input[e][kt*32 + cg*8 .. +8]
        bf16x8 bf1[2];
#pragma unroll
        for (int kt = 0; kt < 2; kt++) {
            const float* src = inp + (size_t)eg * 64 + kt * 32 + cg * 8;
            const float4 a0 = *(const float4*)(src);
            const float4 a1 = *(const float4*)(src + 4);
            U4B u;
            u.u.x = cvtpk(a0.x, a0.y); u.u.y = cvtpk(a0.z, a0.w);
            u.u.z = cvtpk(a1.x, a1.y); u.u.w = cvtpk(a1.z, a1.w);
            bf1[kt] = u.b;
        }

        // ---- Layer 1: all 128 hid cols for 16 edges (16 MFMA) ----
        f32x4 acc1[8];
#pragma unroll
        for (int i = 0; i < 8; i++) acc1[i] = (f32x4){0.f, 0.f, 0.f, 0.f};
#pragma unroll
        for (int kt = 0; kt < 2; kt++) {
#pragma unroll
            for (int ht = 0; ht < 8; ht++) {
                const bf16x8 af = *(const bf16x8*)(W1p + (size_t)(kt * 8 + ht) * 512 + l * 8);
                acc1[ht] = __builtin_amdgcn_mfma_f32_16x16x32_bf16(af, bf1[kt], acc1[ht], 0, 0, 0);
            }
        }

        // ---- bias + silu -> s_h (in-wave, no barrier) ----
#pragma unroll
        for (int ht = 0; ht < 8; ht++) {
            const int hid0 = ht * 16 + cg * 4;
            const float4 bv = *(const float4*)(b1p + hid0);
            const float* bvf = (const float*)&bv;
            float s[4];
#pragma unroll
            for (int r = 0; r < 4; r++) {
                const float v = acc1[ht][r] + bvf[r];
                s[r] = v * __builtin_amdgcn_rcpf(1.0f + __expf(-v));
            }
            const uint2 hv = { cvtpk(s[0], s[1]), cvtpk(s[2], s[3]) };
            *(uint2*)(ph + ((e * 256 + hid0 * 2) ^ sw)) = hv;
        }

        // ---- Layer 2: acc2 += W2 @ H, K = 128 (32 MFMA) ----
#pragma unroll
        for (int kt = 0; kt < 4; kt++) {
            const bf16x8 hf = *(const bf16x8*)(ph + ((e * 256 + kt * 64 + cg * 16) ^ sw));
#pragma unroll
            for (int ct = 0; ct < 8; ct++) {
                const bf16x8 af = *(const bf16x8*)(W2p + (size_t)(kt * 8 + ct) * 512 + l * 8);
                acc2[ct] = __builtin_amdgcn_mfma_f32_16x16x32_bf16(af, hf, acc2[ct], 0, 0, 0);
            }
        }
    }

    // ---- Attention: per-head partial sums, 2 shuffles per head ----
    float vh[4] = {0.f, 0.f, 0.f, 0.f};
#pragma unroll
    for (int ct = 0; ct < 8; ct++) {
        const us4 pv = *(const us4*)(pp + ((e * 256 + ct * 32 + cg * 8) ^ sw));
        const int c0 = ct * 16 + cg * 4;
        const float4 br = *(const float4*)(b_rad2 + c0);
        const float4 bs = *(const float4*)(b_sph2 + c0);
        const float* brf = (const float*)&br;
        const float* bsf = (const float*)&bs;
        float sum = 0.f;
#pragma unroll
        for (int r = 0; r < 4; r++)
            sum = fmaf(bf2f(pv[r]), acc2[ct][r] + brf[r] + bsf[r], sum);
        vh[ct >> 1] += sum;
    }
#pragma unroll
    for (int h = 0; h < 4; h++) {
        vh[h] += __shfl_xor(vh[h], 16, 64);
        vh[h] += __shfl_xor(vh[h], 32, 64);
        // 1/sqrt(32) * 1/32
        vh[h] *= cut * 0.005524271728019903f;
    }

    // ---- Scatter (coalesced): 4 lanes (cg) cover one edge's 16 comps ----
    {
        const float4 sh = *(const float4*)(edge_sh + (size_t)eg * 16 + cg * 4);
        const float* shf = (const float*)&sh;
#pragma unroll
        for (int j = 0; j < 4; j++) {
            const int comp = cg * 4 + j;
            const int head = (comp == 0) ? 0 : (comp < 4) ? 1 : (comp < 9) ? 2 : 3;
            atomicAdd(&out[(size_t)rn * 16 + comp], shf[j] * vh[head]);
        }
    }
}

// ---------------------------------------------------------------------------
extern "C" void kernel_launch(void* const* d_in, const int* in_sizes, int n_in,
                              void* d_out, int out_size, void* d_ws, size_t ws_size,
                              hipStream_t stream)
{
    const float* edge_sh    = (const float*)d_in[0];
    const float* node_feats = (const float*)d_in[1];
    const float* edge_feats = (const float*)d_in[2];
    const float* chi_scalar = (const float*)d_in[3];
    const float* cutoffs    = (const float*)d_in[4];
    const int*   senders    = (const int*)d_in[5];
    const int*   receivers  = (const int*)d_in[6];
    const float* W_rad1 = (const float*)d_in[7];
    const float* b_rad1 = (const float*)d_in[8];
    const float* W_rad2 = (const float*)d_in[9];
    const float* b_rad2 = (const float*)d_in[10];
    const float* W_sph1 = (const float*)d_in[11];
    const float* b_sph1 = (const float*)d_in[12];
    const float* W_sph2 = (const float*)d_in[13];
    const float* b_sph2 = (const float*)d_in[14];
    const float* Wq     = (const float*)d_in[15];
    const float* Wk     = (const float*)d_in[16];

    float* out = (float*)d_out;
    unsigned short* qbuf = (unsigned short*)d_ws;        // [N,128] bf16
    unsigned short* kbuf = qbuf + (size_t)NNODES * DDIM; // [N,128] bf16
    unsigned short* w1r  = kbuf + (size_t)NNODES * DDIM;
    unsigned short* w1s  = w1r + 16 * 512;
    unsigned short* w2r  = w1s + 16 * 512;
    unsigned short* w2s  = w2r + 32 * 512;

    hipMemsetAsync(out, 0, (size_t)out_size * sizeof(float), stream);

    pack_weights<<<16, 256, 0, stream>>>(W_rad1, w1r);
    pack_weights<<<16, 256, 0, stream>>>(W_sph1, w1s);
    pack_weights<<<32, 256, 0, stream>>>(W_rad2, w2r);
    pack_weights<<<32, 256, 0, stream>>>(W_sph2, w2s);

    qk_proj_kernel<<<NNODES / TN, 256, 0, stream>>>(node_feats, Wq, Wk, qbuf, kbuf);

    edge_kernel<<<NEDGES / BE, 64, 0, stream>>>(
        edge_sh, cutoffs, senders, receivers, edge_feats, chi_scalar,
        w1r, w1s, w2r, w2s, b_rad1, b_sph1, b_rad2, b_sph2,
        qbuf, kbuf, out);
}

// Round 9
// 389.922 us; speedup vs baseline: 1.0175x; 1.0175x over previous
//
#include <hip/hip_runtime.h>
#include <cmath>

#define NNODES 20000
#define NEDGES 640000
#define DDIM   128
#define TN     16    // nodes per block in qk kernel
#define BE     64    // edges per block in edge kernel

typedef __attribute__((ext_vector_type(8))) short bf16x8;
typedef __attribute__((ext_vector_type(4))) float f32x4;
typedef __attribute__((ext_vector_type(4))) unsigned short us4;

union U4B { uint4 u; bf16x8 b; };

__device__ __forceinline__ unsigned short f2bf(float x) {
    union { float f; unsigned u; } v; v.f = x;
    unsigned r = v.u + 0x7FFFu + ((v.u >> 16) & 1u);   // RNE
    return (unsigned short)(r >> 16);
}
__device__ __forceinline__ float bf2f(unsigned short h) {
    union { unsigned u; float f; } v; v.u = ((unsigned)h) << 16; return v.f;
}
__device__ __forceinline__ float lo2f(unsigned u) {   // low bf16 of packed word
    union { unsigned u; float f; } v; v.u = u << 16; return v.f;
}
__device__ __forceinline__ float hi2f(unsigned u) {   // high bf16 of packed word
    union { unsigned u; float f; } v; v.u = u & 0xffff0000u; return v.f;
}
// packed bf16 pair via HW instruction: D[15:0]=bf16(lo), D[31:16]=bf16(hi)
__device__ __forceinline__ unsigned cvtpk(float lo, float hi) {
    unsigned r;
    asm("v_cvt_pk_bf16_f32 %0, %1, %2" : "=v"(r) : "v"(lo), "v"(hi));
    return r;
}

// ---------------------------------------------------------------------------
// Pack fp32 weight matrix [K x 128] into bf16 MFMA A-fragment layout.
// frame f = kt*8 + nt; elem (lane,i): W[kt*32 + (lane>>4)*8 + i][nt*16 + (lane&15)]
// ---------------------------------------------------------------------------
__global__ void pack_weights(const float* __restrict__ W, unsigned short* __restrict__ dst)
{
    const int f  = blockIdx.x;
    const int kt = f >> 3, nt = f & 7;
    const int t  = threadIdx.x;
#pragma unroll
    for (int ii = 0; ii < 2; ii++) {
        const int idx  = t * 2 + ii;          // 0..511
        const int lane = idx >> 3, i = idx & 7;
        const int k = kt * 32 + (lane >> 4) * 8 + i;
        const int n = nt * 16 + (lane & 15);
        dst[f * 512 + idx] = f2bf(W[k * 128 + n]);
    }
}

// ---------------------------------------------------------------------------
// q = node_feats @ Wq, k = node_feats @ Wk  -> bf16 [N,128] each.
// ---------------------------------------------------------------------------
__global__ __launch_bounds__(256) void qk_proj_kernel(
    const float* __restrict__ nf, const float* __restrict__ Wq,
    const float* __restrict__ Wk, unsigned short* __restrict__ qbuf,
    unsigned short* __restrict__ kbuf)
{
    __shared__ float s_nf[TN * DDIM];
    const int t  = threadIdx.x;
    const int n0 = blockIdx.x * TN;
    {
        const float4* src = (const float4*)(nf + (size_t)n0 * DDIM);
        float4* dst = (float4*)s_nf;
        for (int i = t; i < TN * DDIM / 4; i += 256) dst[i] = src[i];
    }
    __syncthreads();

    const int j = t & 127;
    const float* W = (t < 128) ? Wq : Wk;
    float acc[TN];
#pragma unroll
    for (int n = 0; n < TN; n++) acc[n] = 0.f;

    for (int k = 0; k < DDIM; k += 4) {
        const float w0 = W[(k + 0) * DDIM + j];
        const float w1 = W[(k + 1) * DDIM + j];
        const float w2 = W[(k + 2) * DDIM + j];
        const float w3 = W[(k + 3) * DDIM + j];
#pragma unroll
        for (int n = 0; n < TN; n++) {
            const float4 f = *(const float4*)&s_nf[n * DDIM + k];
            acc[n] = fmaf(f.w, w3, fmaf(f.z, w2, fmaf(f.y, w1, fmaf(f.x, w0, acc[n]))));
        }
    }
    unsigned short* outp = (t < 128) ? qbuf : kbuf;
    for (int n = 0; n < TN; n++) outp[(size_t)(n0 + n) * DDIM + j] = f2bf(acc[n]);
}

// ---------------------------------------------------------------------------
// Fused edge kernel, 2-barrier merged-path version. 64 edges/block, 4 waves.
// H = [64][256] (rad||sph) in LDS; wave w computes H cols [w*64, w*64+64)
// (L1 inputs direct from global), then final-w cols [w*32, w*32+32) over
// K=256. Wave w == attention head w. q*k kept in registers (no s_p/s_a).
// ---------------------------------------------------------------------------
__global__ __launch_bounds__(256, 4) void edge_kernel(
    const float* __restrict__ edge_sh, const float* __restrict__ cutoffs,
    const int* __restrict__ senders, const int* __restrict__ receivers,
    const float* __restrict__ edge_feats, const float* __restrict__ chi_scalar,
    const unsigned short* __restrict__ w1r, const unsigned short* __restrict__ w1s,
    const unsigned short* __restrict__ w2r, const unsigned short* __restrict__ w2s,
    const float* __restrict__ b_rad1, const float* __restrict__ b_sph1,
    const float* __restrict__ b_rad2, const float* __restrict__ b_sph2,
    const unsigned short* __restrict__ qbuf, const unsigned short* __restrict__ kbuf,
    float* __restrict__ out)
{
    __shared__ unsigned short s_h[64 * 256];   // 32 KB [edge][256 hid] swizzled
    __shared__ float s_alpha[64][4];           // 1 KB
    char* ph = (char*)s_h;

    const int t  = threadIdx.x;
    const int w  = t >> 6;        // wave id == head id
    const int l  = t & 63;
    const int el = l & 15;
    const int rg = l >> 4;        // 0..3
    const int eb = blockIdx.x * BE;

    // ---- lane's 4 edges: indices + cutoffs ----
    int rn[4], sn[4];
    float cut[4];
#pragma unroll
    for (int et = 0; et < 4; et++) {
        const int eg = eb + et * 16 + el;
        rn[et] = receivers[eg];
        sn[et] = senders[eg];
        cut[et] = cutoffs[eg];
    }

    // ---- q/k gathers in C-frag layout (consumed just before sync1) ----
    const int c0base = w * 32 + rg * 4;
    us4 qv[2][4], kv[2][4];
#pragma unroll
    for (int et = 0; et < 4; et++)
#pragma unroll
        for (int ct = 0; ct < 2; ct++) {
            qv[ct][et] = *(const us4*)(qbuf + (size_t)rn[et] * 128 + c0base + ct * 16);
            kv[ct][et] = *(const us4*)(kbuf + (size_t)sn[et] * 128 + c0base + ct * 16);
        }

    // ---- Layer 1 (merged paths): wave w -> H cols [w*64, w*64+64) ----
    // path = w>>1 selects input (ef/chi) and W1; done in 2 sub-batches of
    // 2 col-tiles to bound acc1 at 32 VGPRs.
    const int path   = w >> 1;
    const int ntbase = (w & 1) * 4;
    const float* inp = path ? chi_scalar : edge_feats;
    const unsigned short* W1p = path ? w1s : w1r;
    const float* b1p = path ? b_sph1 : b_rad1;

#pragma unroll
    for (int nb = 0; nb < 2; nb++) {
        f32x4 acc1[2][4];
#pragma unroll
        for (int j = 0; j < 2; j++)
#pragma unroll
            for (int et = 0; et < 4; et++)
                acc1[j][et] = (f32x4){0.f, 0.f, 0.f, 0.f};

#pragma unroll
        for (int kt = 0; kt < 2; kt++) {
            bf16x8 bfrag[4];
#pragma unroll
            for (int et = 0; et < 4; et++) {
                const float* src = inp + (size_t)(eb + et * 16 + el) * 64 + kt * 32 + rg * 8;
                const float4 a0 = *(const float4*)src;
                const float4 a1 = *(const float4*)(src + 4);
                U4B u;
                u.u.x = cvtpk(a0.x, a0.y); u.u.y = cvtpk(a0.z, a0.w);
                u.u.z = cvtpk(a1.x, a1.y); u.u.w = cvtpk(a1.z, a1.w);
                bfrag[et] = u.b;
            }
#pragma unroll
            for (int j = 0; j < 2; j++) {
                const int nt = ntbase + nb * 2 + j;
                const bf16x8 af = *(const bf16x8*)(W1p + (size_t)(kt * 8 + nt) * 512 + l * 8);
#pragma unroll
                for (int et = 0; et < 4; et++)
                    acc1[j][et] = __builtin_amdgcn_mfma_f32_16x16x32_bf16(
                        af, bfrag[et], acc1[j][et], 0, 0, 0);
            }
        }

        // bias + silu -> H slice (no barrier yet)
#pragma unroll
        for (int j = 0; j < 2; j++) {
            const int nt = ntbase + nb * 2 + j;
            const int hc = nt * 16 + rg * 4;          // col within path's 128
            const float4 bv = *(const float4*)(b1p + hc);
            const float* bvf = (const float*)&bv;
#pragma unroll
            for (int et = 0; et < 4; et++) {
                const int e = et * 16 + el;
                float s[4];
#pragma unroll
                for (int r = 0; r < 4; r++) {
                    const float v = acc1[j][et][r] + bvf[r];
                    s[r] = v * __builtin_amdgcn_rcpf(1.0f + __expf(-v));
                }
                const uint2 hv = { cvtpk(s[0], s[1]), cvtpk(s[2], s[3]) };
                *(uint2*)(ph + ((e * 512 + path * 256 + hc * 2) ^ ((e & 7) << 4))) = hv;
            }
        }
    }

    // ---- fold q*k into 16 packed regs (gathers have had all of L1 to land) ----
    uint2 p2[2][4];
#pragma unroll
    for (int ct = 0; ct < 2; ct++)
#pragma unroll
        for (int et = 0; et < 4; et++) {
            const us4 q = qv[ct][et], k = kv[ct][et];
            p2[ct][et].x = cvtpk(bf2f(q[0]) * bf2f(k[0]), bf2f(q[1]) * bf2f(k[1]));
            p2[ct][et].y = cvtpk(bf2f(q[2]) * bf2f(k[2]), bf2f(q[3]) * bf2f(k[3]));
        }
    __syncthreads();   // sync 1: H complete (gathers drained too)

    // ---- Layer 2: acc2 = W2cat[cols w*32..+32] @ H, K = 256 ----
    f32x4 acc2[2][4];
#pragma unroll
    for (int ct = 0; ct < 2; ct++)
#pragma unroll
        for (int et = 0; et < 4; et++)
            acc2[ct][et] = (f32x4){0.f, 0.f, 0.f, 0.f};

    f32x4 b2s[2];
#pragma unroll
    for (int ct = 0; ct < 2; ct++) {
        const float4 br = *(const float4*)(b_rad2 + c0base + ct * 16);
        const float4 bs = *(const float4*)(b_sph2 + c0base + ct * 16);
        b2s[ct] = (f32x4){ br.x + bs.x, br.y + bs.y, br.z + bs.z, br.w + bs.w };
    }

#pragma unroll
    for (int kt = 0; kt < 8; kt++) {
        const unsigned short* W2p = (kt < 4) ? w2r : w2s;
        const int fkt = kt & 3;
        bf16x8 hfrag[4];
#pragma unroll
        for (int et = 0; et < 4; et++) {
            const int e = et * 16 + el;
            hfrag[et] = *(const bf16x8*)(ph + ((e * 512 + kt * 64 + rg * 16) ^ ((e & 7) << 4)));
        }
#pragma unroll
        for (int ct = 0; ct < 2; ct++) {
            const bf16x8 af = *(const bf16x8*)(W2p + (size_t)(fkt * 8 + w * 2 + ct) * 512 + l * 8);
#pragma unroll
            for (int et = 0; et < 4; et++)
                acc2[ct][et] = __builtin_amdgcn_mfma_f32_16x16x32_bf16(
                    af, hfrag[et], acc2[ct][et], 0, 0, 0);
        }
    }

    // ---- Attention: alpha[e][w] from registers ----
#pragma unroll
    for (int et = 0; et < 4; et++) {
        float vsum = 0.f;
#pragma unroll
        for (int ct = 0; ct < 2; ct++) {
            const uint2 p = p2[ct][et];
            vsum = fmaf(lo2f(p.x), acc2[ct][et][0] + b2s[ct][0], vsum);
            vsum = fmaf(hi2f(p.x), acc2[ct][et][1] + b2s[ct][1], vsum);
            vsum = fmaf(lo2f(p.y), acc2[ct][et][2] + b2s[ct][2], vsum);
            vsum = fmaf(hi2f(p.y), acc2[ct][et][3] + b2s[ct][3], vsum);
        }
        vsum += __shfl_xor(vsum, 16, 64);
        vsum += __shfl_xor(vsum, 32, 64);
        if (l < 16) {
            // 1/sqrt(32) * 1/32
            s_alpha[et * 16 + l][w] = vsum * cut[et] * 0.005524271728019903f;
        }
    }
    __syncthreads();   // sync 2

    // ---- Scatter (coalesced): 4 adjacent lanes cover one edge's 16 comps ----
    {
        const int e   = t >> 2;
        const int c0q = t & 3;
        const int eg  = eb + e;
        const int rv  = receivers[eg];
        const float4 sh = *(const float4*)(edge_sh + (size_t)eg * 16 + c0q * 4);
        const float* shf = (const float*)&sh;
#pragma unroll
        for (int j = 0; j < 4; j++) {
            const int comp = c0q * 4 + j;
            const int head = (comp == 0) ? 0 : (comp < 4) ? 1 : (comp < 9) ? 2 : 3;
            atomicAdd(&out[(size_t)rv * 16 + comp], shf[j] * s_alpha[e][head]);
        }
    }
}

// ---------------------------------------------------------------------------
extern "C" void kernel_launch(void* const* d_in, const int* in_sizes, int n_in,
                              void* d_out, int out_size, void* d_ws, size_t ws_size,
                              hipStream_t stream)
{
    const float* edge_sh    = (const float*)d_in[0];
    const float* node_feats = (const float*)d_in[1];
    const float* edge_feats = (const float*)d_in[2];
    const float* chi_scalar = (const float*)d_in[3];
    const float* cutoffs    = (const float*)d_in[4];
    const int*   senders    = (const int*)d_in[5];
    const int*   receivers  = (const int*)d_in[6];
    const float* W_rad1 = (const float*)d_in[7];
    const float* b_rad1 = (const float*)d_in[8];
    const float* W_rad2 = (const float*)d_in[9];
    const float* b_rad2 = (const float*)d_in[10];
    const float* W_sph1 = (const float*)d_in[11];
    const float* b_sph1 = (const float*)d_in[12];
    const float* W_sph2 = (const float*)d_in[13];
    const float* b_sph2 = (const float*)d_in[14];
    const float* Wq     = (const float*)d_in[15];
    const float* Wk     = (const float*)d_in[16];

    float* out = (float*)d_out;
    unsigned short* qbuf = (unsigned short*)d_ws;        // [N,128] bf16
    unsigned short* kbuf = qbuf + (size_t)NNODES * DDIM; // [N,128] bf16
    unsigned short* w1r  = kbuf + (size_t)NNODES * DDIM;
    unsigned short* w1s  = w1r + 16 * 512;
    unsigned short* w2r  = w1s + 16 * 512;
    unsigned short* w2s  = w2r + 32 * 512;

    hipMemsetAsync(out, 0, (size_t)out_size * sizeof(float), stream);

    pack_weights<<<16, 256, 0, stream>>>(W_rad1, w1r);
    pack_weights<<<16, 256, 0, stream>>>(W_sph1, w1s);
    pack_weights<<<32, 256, 0, stream>>>(W_rad2, w2r);
    pack_weights<<<32, 256, 0, stream>>>(W_sph2, w2s);

    qk_proj_kernel<<<NNODES / TN, 256, 0, stream>>>(node_feats, Wq, Wk, qbuf, kbuf);

    edge_kernel<<<NEDGES / BE, 256, 0, stream>>>(
        edge_sh, cutoffs, senders, receivers, edge_feats, chi_scalar,
        w1r, w1s, w2r, w2s, b_rad1, b_sph1, b_rad2, b_sph2,
        qbuf, kbuf, out);
}